// Round 4
// baseline (1600.428 us; speedup 1.0000x reference)
//
#include <hip/hip_runtime.h>
#include <stdint.h>

// B=2, SQ=SK=2048, HIDDEN=2048, HEADS=16, HEAD_DIM=128.
// DTYPE MODEL (verified): inputs fp32, mask int32, OUTPUT fp32. Internal bf16 MFMA.
// Round 4: attn 32q/wave (halve LDS re-reads); rope fused into Q/K GEMM epilogue;
// V-transpose fused into V GEMM epilogue (rope/transpose kernels deleted).

#define LOG2E 1.44269504088896340736f

typedef __attribute__((ext_vector_type(8))) short bf16x8;
typedef __attribute__((ext_vector_type(8))) uint16_t u16x8;
typedef __attribute__((ext_vector_type(4))) uint16_t u16x4;
typedef __attribute__((ext_vector_type(4))) float f32x4;

__device__ __forceinline__ uint16_t f2bf(float f) {
  union { float f; uint32_t i; } v; v.f = f;
  uint32_t x = v.i;
  return (uint16_t)((x + 0x7fffu + ((x >> 16) & 1u)) >> 16);  // RTN-even
}
__device__ __forceinline__ void glds16(const void* g, void* l) {
  __builtin_amdgcn_global_load_lds((const __attribute__((address_space(1))) void*)g,
                                   (__attribute__((address_space(3))) void*)l, 16, 0, 0);
}

// fp32 -> bf16, 8 elems/thread, exact grid (n % 2048 == 0).
__global__ __launch_bounds__(256) void convert_f32_bf16(const float* __restrict__ in,
                                                        uint16_t* __restrict__ out) {
  const long i = ((long)blockIdx.x * 256 + threadIdx.x) * 8;
  const f32x4 a = *(const f32x4*)(in + i);
  const f32x4 b = *(const f32x4*)(in + i + 4);
  u16x8 o;
#pragma unroll
  for (int j = 0; j < 4; ++j) { o[j] = f2bf(a[j]); o[4 + j] = f2bf(b[j]); }
  *(u16x8*)(out + i) = o;
}

// Epilogue modes
#define EPI_ROPE 0  // bf16 out with RoPE applied (Q,K GEMMs); C = [M][N] bf16
#define EPI_VT   1  // bf16 out transposed to Vt[(b*16+h)*128+d][s] (V GEMM)
#define EPI_F32  2  // fp32 out (final projection)

// C[m][n] = sum_k A[m][k] * W[n][k];  m97 structure, 128x128 tile, BK=32.
template <int MODE>
__global__ __launch_bounds__(256) void gemm_bt(const uint16_t* __restrict__ A,
                                               const uint16_t* __restrict__ W,
                                               void* __restrict__ Cv,
                                               int M, int N, int K) {
  __shared__ __align__(16) uint16_t As[128 * 32];
  __shared__ __align__(16) uint16_t Bs[128 * 32];
  const int tid = threadIdx.x;
  const int lane = tid & 63;
  const int w = tid >> 6;
  const int r16 = lane & 15, quad = lane >> 4;
  const int m0 = blockIdx.y * 128, n0 = blockIdx.x * 128;
  const int wm = (w >> 1) * 64, wn = (w & 1) * 64;
  f32x4 acc[4][4] = {};
  const int srow = 32 * w + (lane >> 2);
  const int scol = (lane & 3) * 8;
  const uint16_t* Ag = A + (long)(m0 + srow) * K + scol;
  const uint16_t* Wg = W + (long)(n0 + srow) * K + scol;
  uint16_t* AsW = As + 2 * w * 512;
  uint16_t* BsW = Bs + 2 * w * 512;
  for (int k0 = 0; k0 < K; k0 += 32) {
    glds16(Ag + k0, AsW);
    glds16(Ag + k0 + (long)16 * K, AsW + 512);
    glds16(Wg + k0, BsW);
    glds16(Wg + k0 + (long)16 * K, BsW + 512);
    __syncthreads();
    bf16x8 af[4], bfr[4];
#pragma unroll
    for (int mt = 0; mt < 4; ++mt)
      af[mt] = *(const bf16x8*)(As + (wm + mt * 16 + r16) * 32 + quad * 8);
#pragma unroll
    for (int nt = 0; nt < 4; ++nt)
      bfr[nt] = *(const bf16x8*)(Bs + (wn + nt * 16 + r16) * 32 + quad * 8);
#pragma unroll
    for (int mt = 0; mt < 4; ++mt)
#pragma unroll
      for (int nt = 0; nt < 4; ++nt)
        acc[mt][nt] = __builtin_amdgcn_mfma_f32_16x16x32_bf16(af[mt], bfr[nt], acc[mt][nt], 0, 0, 0);
    __syncthreads();
  }

#pragma unroll
  for (int mt = 0; mt < 4; ++mt)
#pragma unroll
    for (int nt = 0; nt < 4; ++nt) {
      const int col = n0 + wn + nt * 16 + r16;
      const int rowbase = m0 + wm + mt * 16 + quad * 4;
      if constexpr (MODE == EPI_F32) {
        float* C = (float*)Cv;
#pragma unroll
        for (int r = 0; r < 4; ++r)
          C[(long)(rowbase + r) * N + col] = acc[mt][nt][r];
      } else if constexpr (MODE == EPI_ROPE) {
        // RoPE: pair partner lives in lane^1 (cols differ in r16 bit0).
        uint16_t* C = (uint16_t*)Cv;
        const int f = (col >> 1) & 63;
        const float inv = exp2f((float)f * (-13.287712379549449f / 64.0f));
        const float sgn = (col & 1) ? 1.0f : -1.0f;
#pragma unroll
        for (int r = 0; r < 4; ++r) {
          const float val = acc[mt][nt][r];
          const float partner = __shfl_xor(val, 1);
          const int s = (rowbase + r) & 2047;
          float sn, cs;
          sincosf((float)s * inv, &sn, &cs);
          C[(long)(rowbase + r) * N + col] = f2bf(val * cs + sgn * partner * sn);
        }
      } else {  // EPI_VT: Vt[((b*16+h)*128+d)][s], 4 consecutive s packed per lane
        uint16_t* Vt = (uint16_t*)Cv;
        const int h = col >> 7, d = col & 127;
        const int b = rowbase >> 11, s = rowbase & 2047;
        u16x4 pk;
#pragma unroll
        for (int r = 0; r < 4; ++r) pk[r] = f2bf(acc[mt][nt][r]);
        *(u16x4*)(Vt + (long)((b * 16 + h) * 128 + d) * 2048 + s) = pk;
      }
    }
}

// Flash attention v3. Block = (b, h, 128 queries) = 4 waves x 32 queries.
// 64-key tiles, fixed-shift softmax, swizzled LDS. LDS = 16K+16K+16K = 49152 B.
__global__ __launch_bounds__(256) void attn_kernel(const uint16_t* __restrict__ Q,
                                                   const uint16_t* __restrict__ K,
                                                   const uint16_t* __restrict__ Vt,
                                                   const int* __restrict__ mask,
                                                   uint16_t* __restrict__ O) {
  __shared__ __align__(16) uint16_t Ks[64 * 128];    // [key][chunk ^ (key&7)]
  __shared__ __align__(16) uint16_t Vts[128 * 64];   // [dim][keychunk ^ (dim&7)]
  __shared__ __align__(16) uint16_t Ps[4][32 * 64];  // per-wave P [qrow][kchunk ^ (row&7)]
  const int tid = threadIdx.x;
  const int lane = tid & 63;
  const int w = tid >> 6;
  const int r16 = lane & 15, quad = lane >> 4;
  const int h = blockIdx.y, b = blockIdx.z;
  const int qbase = blockIdx.x * 128 + w * 32;
  const float cs_exp = 0.088388347648318447f * LOG2E;  // (1/sqrt(128)) * log2(e)

  bf16x8 qf[2][4];
#pragma unroll
  for (int t = 0; t < 2; ++t) {
    const uint16_t* qb = Q + ((long)(b * 2048 + qbase + t * 16 + r16)) * 2048 + h * 128 + quad * 8;
#pragma unroll
    for (int c = 0; c < 4; ++c) qf[t][c] = *(const bf16x8*)(qb + c * 32);
  }
  f32x4 oacc[2][8] = {};
  float li[2][4] = {};

  uint16_t* PsW = &Ps[w][0];
  const int* mrow = mask + b * 2048;
  const long vt_base = (long)((b * 16 + h) * 128) * 2048;
  const int vt_dim = (lane >> 3);           // 0..7 within each 8-dim chunk
  const int vt_swz = (lane & 7) ^ vt_dim;   // global key-chunk this lane fetches

  for (int kt = 0; kt < 32; ++kt) {
    const int k0 = kt * 64;
    // stage K tile: 64 keys x 256B; wave w stages 1KB chunks 4w..4w+3
#pragma unroll
    for (int i = 0; i < 4; ++i) {
      const int key0 = 16 * w + 4 * i + quad;
      const int g = r16 ^ (key0 & 7);
      glds16(K + ((long)(b * 2048 + k0 + key0)) * 2048 + h * 128 + 8 * g,
             Ks + (4 * w + i) * 512);
    }
    // stage Vt tile: 128 dims x 128B; wave w stages dims 32w..32w+31
#pragma unroll
    for (int i = 0; i < 4; ++i) {
      const int dim = 32 * w + 8 * i + vt_dim;
      glds16(Vt + vt_base + (long)dim * 2048 + k0 + 8 * vt_swz,
             Vts + (4 * w + i) * 512);
    }
    __syncthreads();

    // S = Q K^T (two 16-q row tiles share kf), p = exp2(s*cs_exp), per-lane l
#pragma unroll
    for (int ct = 0; ct < 4; ++ct) {
      const int key = ct * 16 + r16;
      const int kb = key & 7;
      bf16x8 kf[4];
#pragma unroll
      for (int c = 0; c < 4; ++c)
        kf[c] = *(const bf16x8*)(Ks + key * 128 + ((4 * c + quad) ^ kb) * 8);
      const int mv = mrow[k0 + key];
      const int pc = ct * 2 + (r16 >> 3);
#pragma unroll
      for (int t = 0; t < 2; ++t) {
        f32x4 s = {};
#pragma unroll
        for (int c = 0; c < 4; ++c)
          s = __builtin_amdgcn_mfma_f32_16x16x32_bf16(qf[t][c], kf[c], s, 0, 0, 0);
#pragma unroll
        for (int r = 0; r < 4; ++r) {
          const float arg = mv ? s[r] * cs_exp : -__builtin_inff();
          const float p = exp2f(arg);
          li[t][r] += p;
          const int row = t * 16 + quad * 4 + r;
          PsW[row * 64 + ((pc ^ (row & 7)) * 8) + (r16 & 7)] = f2bf(p);
        }
      }
    }

    // O += P V : vf shared across both row tiles
    bf16x8 pa[2][2];
#pragma unroll
    for (int t = 0; t < 2; ++t)
#pragma unroll
      for (int half = 0; half < 2; ++half)
        pa[t][half] = *(const bf16x8*)(PsW + (t * 16 + r16) * 64 +
                                       (((half * 4 + quad) ^ (r16 & 7)) * 8));
#pragma unroll
    for (int nt = 0; nt < 8; ++nt) {
      const int dim = nt * 16 + r16;
#pragma unroll
      for (int half = 0; half < 2; ++half) {
        bf16x8 vf = *(const bf16x8*)(Vts + dim * 64 + (((half * 4 + quad) ^ (r16 & 7)) * 8));
#pragma unroll
        for (int t = 0; t < 2; ++t)
          oacc[t][nt] = __builtin_amdgcn_mfma_f32_16x16x32_bf16(pa[t][half], vf, oacc[t][nt], 0, 0, 0);
      }
    }
    __syncthreads();
  }

  // reduce row sums across the 16 key-lanes (fixed-shift softmax: no rescaling)
#pragma unroll
  for (int off = 1; off < 16; off <<= 1)
#pragma unroll
    for (int t = 0; t < 2; ++t)
#pragma unroll
      for (int r = 0; r < 4; ++r) li[t][r] += __shfl_xor(li[t][r], off);

#pragma unroll
  for (int t = 0; t < 2; ++t) {
    uint16_t* ob = O + ((long)(b * 2048 + qbase + t * 16)) * 2048 + h * 128;
    float inv_l[4];
#pragma unroll
    for (int r = 0; r < 4; ++r) inv_l[r] = 1.0f / li[t][r];
#pragma unroll
    for (int nt = 0; nt < 8; ++nt)
#pragma unroll
      for (int r = 0; r < 4; ++r)
        ob[(long)(quad * 4 + r) * 2048 + nt * 16 + r16] = f2bf(oacc[t][nt][r] * inv_l[r]);
  }
}

extern "C" void kernel_launch(void* const* d_in, const int* in_sizes, int n_in,
                              void* d_out, int out_size, void* d_ws, size_t ws_size,
                              hipStream_t stream) {
  const float* x   = (const float*)d_in[0];
  const float* enc = (const float*)d_in[1];
  const int*   msk = (const int*)d_in[2];
  const float* Wq  = (const float*)d_in[3];
  const float* Wk  = (const float*)d_in[4];
  const float* Wv  = (const float*)d_in[5];
  const float* Wo  = (const float*)d_in[6];
  float* out = (float*)d_out;

  const long NELT = 8L * 1024 * 1024;  // 4096 x 2048
  const long WELT = 4L * 1024 * 1024;  // 2048 x 2048
  uint16_t* Qb   = (uint16_t*)d_ws;
  uint16_t* Kb   = Qb + NELT;
  uint16_t* Vtb  = Kb + NELT;   // V GEMM writes transposed directly
  uint16_t* xb   = Vtb + NELT;
  uint16_t* encb = xb + NELT;
  uint16_t* Wb   = encb + NELT;
  uint16_t* Ob   = xb;  // x dead after Q-GEMM; reuse for attention output

  const dim3 gb(16, 32);  // N/128, M/128
  const int CB_ACT = (int)(NELT / 2048);
  const int CB_W   = (int)(WELT / 2048);

  convert_f32_bf16<<<CB_ACT, 256, 0, stream>>>(x, xb);
  convert_f32_bf16<<<CB_W, 256, 0, stream>>>(Wq, Wb);
  gemm_bt<EPI_ROPE><<<gb, 256, 0, stream>>>(xb, Wb, Qb, 4096, 2048, 2048);

  convert_f32_bf16<<<CB_ACT, 256, 0, stream>>>(enc, encb);
  convert_f32_bf16<<<CB_W, 256, 0, stream>>>(Wk, Wb);
  gemm_bt<EPI_ROPE><<<gb, 256, 0, stream>>>(encb, Wb, Kb, 4096, 2048, 2048);

  convert_f32_bf16<<<CB_W, 256, 0, stream>>>(Wv, Wb);
  gemm_bt<EPI_VT><<<gb, 256, 0, stream>>>(encb, Wb, Vtb, 4096, 2048, 2048);

  attn_kernel<<<dim3(16, 16, 2), 256, 0, stream>>>(Qb, Kb, Vtb, msk, Ob);

  convert_f32_bf16<<<CB_W, 256, 0, stream>>>(Wo, Wb);
  gemm_bt<EPI_F32><<<gb, 256, 0, stream>>>(Ob, Wb, out, 4096, 2048, 2048);
}

// Round 5
// 569.475 us; speedup vs baseline: 2.8104x; 2.8104x over previous
//
#include <hip/hip_runtime.h>
#include <stdint.h>

// B=2, SQ=SK=2048, HIDDEN=2048, HEADS=16, HEAD_DIM=128.
// DTYPE MODEL (verified): inputs fp32, mask int32, OUTPUT fp32. Internal bf16 MFMA.
// Round 5: round-4 structure, but NO LIBCALLS in device code. sincosf in the GEMM
// epilogue was a real call -> compiler capped kernel at 28 VGPR and spilled the
// 64-VGPR accumulator through scratch in the K-loop (2.1 GB writes). Replaced with
// raw v_sin/v_cos/v_exp builtins + explicit fract range reduction.

#define LOG2E 1.44269504088896340736f
#define INV2PI 0.15915494309189535f

typedef __attribute__((ext_vector_type(8))) short bf16x8;
typedef __attribute__((ext_vector_type(8))) uint16_t u16x8;
typedef __attribute__((ext_vector_type(4))) uint16_t u16x4;
typedef __attribute__((ext_vector_type(4))) float f32x4;

__device__ __forceinline__ uint16_t f2bf(float f) {
  union { float f; uint32_t i; } v; v.f = f;
  uint32_t x = v.i;
  return (uint16_t)((x + 0x7fffu + ((x >> 16) & 1u)) >> 16);  // RTN-even
}
__device__ __forceinline__ void glds16(const void* g, void* l) {
  __builtin_amdgcn_global_load_lds((const __attribute__((address_space(1))) void*)g,
                                   (__attribute__((address_space(3))) void*)l, 16, 0, 0);
}

// fp32 -> bf16, 8 elems/thread, exact grid (n % 2048 == 0).
__global__ __launch_bounds__(256) void convert_f32_bf16(const float* __restrict__ in,
                                                        uint16_t* __restrict__ out) {
  const long i = ((long)blockIdx.x * 256 + threadIdx.x) * 8;
  const f32x4 a = *(const f32x4*)(in + i);
  const f32x4 b = *(const f32x4*)(in + i + 4);
  u16x8 o;
#pragma unroll
  for (int j = 0; j < 4; ++j) { o[j] = f2bf(a[j]); o[4 + j] = f2bf(b[j]); }
  *(u16x8*)(out + i) = o;
}

// Epilogue modes
#define EPI_ROPE 0  // bf16 out with RoPE applied (Q,K GEMMs); C = [M][N] bf16
#define EPI_VT   1  // bf16 out transposed to Vt[(b*16+h)*128+d][s] (V GEMM)
#define EPI_F32  2  // fp32 out (final projection)

// C[m][n] = sum_k A[m][k] * W[n][k];  m97 structure, 128x128 tile, BK=32.
template <int MODE>
__global__ __launch_bounds__(256) void gemm_bt(const uint16_t* __restrict__ A,
                                               const uint16_t* __restrict__ W,
                                               void* __restrict__ Cv,
                                               int M, int N, int K) {
  __shared__ __align__(16) uint16_t As[128 * 32];
  __shared__ __align__(16) uint16_t Bs[128 * 32];
  const int tid = threadIdx.x;
  const int lane = tid & 63;
  const int w = tid >> 6;
  const int r16 = lane & 15, quad = lane >> 4;
  const int m0 = blockIdx.y * 128, n0 = blockIdx.x * 128;
  const int wm = (w >> 1) * 64, wn = (w & 1) * 64;
  f32x4 acc[4][4] = {};
  const int srow = 32 * w + (lane >> 2);
  const int scol = (lane & 3) * 8;
  const uint16_t* Ag = A + (long)(m0 + srow) * K + scol;
  const uint16_t* Wg = W + (long)(n0 + srow) * K + scol;
  uint16_t* AsW = As + 2 * w * 512;
  uint16_t* BsW = Bs + 2 * w * 512;
  for (int k0 = 0; k0 < K; k0 += 32) {
    glds16(Ag + k0, AsW);
    glds16(Ag + k0 + (long)16 * K, AsW + 512);
    glds16(Wg + k0, BsW);
    glds16(Wg + k0 + (long)16 * K, BsW + 512);
    __syncthreads();
    bf16x8 af[4], bfr[4];
#pragma unroll
    for (int mt = 0; mt < 4; ++mt)
      af[mt] = *(const bf16x8*)(As + (wm + mt * 16 + r16) * 32 + quad * 8);
#pragma unroll
    for (int nt = 0; nt < 4; ++nt)
      bfr[nt] = *(const bf16x8*)(Bs + (wn + nt * 16 + r16) * 32 + quad * 8);
#pragma unroll
    for (int mt = 0; mt < 4; ++mt)
#pragma unroll
      for (int nt = 0; nt < 4; ++nt)
        acc[mt][nt] = __builtin_amdgcn_mfma_f32_16x16x32_bf16(af[mt], bfr[nt], acc[mt][nt], 0, 0, 0);
    __syncthreads();
  }

#pragma unroll
  for (int mt = 0; mt < 4; ++mt)
#pragma unroll
    for (int nt = 0; nt < 4; ++nt) {
      const int col = n0 + wn + nt * 16 + r16;
      const int rowbase = m0 + wm + mt * 16 + quad * 4;
      if constexpr (MODE == EPI_F32) {
        float* C = (float*)Cv;
#pragma unroll
        for (int r = 0; r < 4; ++r)
          C[(long)(rowbase + r) * N + col] = acc[mt][nt][r];
      } else if constexpr (MODE == EPI_ROPE) {
        // RoPE: pair partner lives in lane^1 (cols differ in r16 bit0).
        // All-inline transcendentals: v_exp, v_fract, v_sin, v_cos (no libcalls!).
        uint16_t* C = (uint16_t*)Cv;
        const int f = (col >> 1) & 63;
        const float inv = __builtin_amdgcn_exp2f((float)f * (-13.287712379549449f / 64.0f));
        const float sgn = (col & 1) ? 1.0f : -1.0f;
#pragma unroll
        for (int r = 0; r < 4; ++r) {
          const float val = acc[mt][nt][r];
          const float partner = __shfl_xor(val, 1);
          const int s = (rowbase + r) & 2047;
          const float rev = __builtin_amdgcn_fractf((float)s * inv * INV2PI);
          const float sn = __builtin_amdgcn_sinf(rev);   // sin(2*pi*rev)
          const float cs = __builtin_amdgcn_cosf(rev);   // cos(2*pi*rev)
          C[(long)(rowbase + r) * N + col] = f2bf(val * cs + sgn * partner * sn);
        }
      } else {  // EPI_VT: Vt[((b*16+h)*128+d)][s], 4 consecutive s packed per lane
        uint16_t* Vt = (uint16_t*)Cv;
        const int h = col >> 7, d = col & 127;
        const int b = rowbase >> 11, s = rowbase & 2047;
        u16x4 pk;
#pragma unroll
        for (int r = 0; r < 4; ++r) pk[r] = f2bf(acc[mt][nt][r]);
        *(u16x4*)(Vt + (long)((b * 16 + h) * 128 + d) * 2048 + s) = pk;
      }
    }
}

// Flash attention v3. Block = (b, h, 128 queries) = 4 waves x 32 queries.
// 64-key tiles, fixed-shift softmax, swizzled LDS. LDS = 16K+16K+16K = 49152 B.
__global__ __launch_bounds__(256) void attn_kernel(const uint16_t* __restrict__ Q,
                                                   const uint16_t* __restrict__ K,
                                                   const uint16_t* __restrict__ Vt,
                                                   const int* __restrict__ mask,
                                                   uint16_t* __restrict__ O) {
  __shared__ __align__(16) uint16_t Ks[64 * 128];    // [key][chunk ^ (key&7)]
  __shared__ __align__(16) uint16_t Vts[128 * 64];   // [dim][keychunk ^ (dim&7)]
  __shared__ __align__(16) uint16_t Ps[4][32 * 64];  // per-wave P [qrow][kchunk ^ (row&7)]
  const int tid = threadIdx.x;
  const int lane = tid & 63;
  const int w = tid >> 6;
  const int r16 = lane & 15, quad = lane >> 4;
  const int h = blockIdx.y, b = blockIdx.z;
  const int qbase = blockIdx.x * 128 + w * 32;
  const float cs_exp = 0.088388347648318447f * LOG2E;  // (1/sqrt(128)) * log2(e)

  bf16x8 qf[2][4];
#pragma unroll
  for (int t = 0; t < 2; ++t) {
    const uint16_t* qb = Q + ((long)(b * 2048 + qbase + t * 16 + r16)) * 2048 + h * 128 + quad * 8;
#pragma unroll
    for (int c = 0; c < 4; ++c) qf[t][c] = *(const bf16x8*)(qb + c * 32);
  }
  f32x4 oacc[2][8] = {};
  float li[2][4] = {};

  uint16_t* PsW = &Ps[w][0];
  const int* mrow = mask + b * 2048;
  const long vt_base = (long)((b * 16 + h) * 128) * 2048;
  const int vt_dim = (lane >> 3);           // 0..7 within each 8-dim chunk
  const int vt_swz = (lane & 7) ^ vt_dim;   // global key-chunk this lane fetches

  for (int kt = 0; kt < 32; ++kt) {
    const int k0 = kt * 64;
    // stage K tile: 64 keys x 256B; wave w stages 1KB chunks 4w..4w+3
#pragma unroll
    for (int i = 0; i < 4; ++i) {
      const int key0 = 16 * w + 4 * i + quad;
      const int g = r16 ^ (key0 & 7);
      glds16(K + ((long)(b * 2048 + k0 + key0)) * 2048 + h * 128 + 8 * g,
             Ks + (4 * w + i) * 512);
    }
    // stage Vt tile: 128 dims x 128B; wave w stages dims 32w..32w+31
#pragma unroll
    for (int i = 0; i < 4; ++i) {
      const int dim = 32 * w + 8 * i + vt_dim;
      glds16(Vt + vt_base + (long)dim * 2048 + k0 + 8 * vt_swz,
             Vts + (4 * w + i) * 512);
    }
    __syncthreads();

    // S = Q K^T (two 16-q row tiles share kf), p = exp2(s*cs_exp), per-lane l
#pragma unroll
    for (int ct = 0; ct < 4; ++ct) {
      const int key = ct * 16 + r16;
      const int kb = key & 7;
      bf16x8 kf[4];
#pragma unroll
      for (int c = 0; c < 4; ++c)
        kf[c] = *(const bf16x8*)(Ks + key * 128 + ((4 * c + quad) ^ kb) * 8);
      const int mv = mrow[k0 + key];
      const int pc = ct * 2 + (r16 >> 3);
#pragma unroll
      for (int t = 0; t < 2; ++t) {
        f32x4 s = {};
#pragma unroll
        for (int c = 0; c < 4; ++c)
          s = __builtin_amdgcn_mfma_f32_16x16x32_bf16(qf[t][c], kf[c], s, 0, 0, 0);
#pragma unroll
        for (int r = 0; r < 4; ++r) {
          const float arg = mv ? s[r] * cs_exp : -__builtin_inff();
          const float p = __builtin_amdgcn_exp2f(arg);
          li[t][r] += p;
          const int row = t * 16 + quad * 4 + r;
          PsW[row * 64 + ((pc ^ (row & 7)) * 8) + (r16 & 7)] = f2bf(p);
        }
      }
    }

    // O += P V : vf shared across both row tiles
    bf16x8 pa[2][2];
#pragma unroll
    for (int t = 0; t < 2; ++t)
#pragma unroll
      for (int half = 0; half < 2; ++half)
        pa[t][half] = *(const bf16x8*)(PsW + (t * 16 + r16) * 64 +
                                       (((half * 4 + quad) ^ (r16 & 7)) * 8));
#pragma unroll
    for (int nt = 0; nt < 8; ++nt) {
      const int dim = nt * 16 + r16;
#pragma unroll
      for (int half = 0; half < 2; ++half) {
        bf16x8 vf = *(const bf16x8*)(Vts + dim * 64 + (((half * 4 + quad) ^ (r16 & 7)) * 8));
#pragma unroll
        for (int t = 0; t < 2; ++t)
          oacc[t][nt] = __builtin_amdgcn_mfma_f32_16x16x32_bf16(pa[t][half], vf, oacc[t][nt], 0, 0, 0);
      }
    }
    __syncthreads();
  }

  // reduce row sums across the 16 key-lanes (fixed-shift softmax: no rescaling)
#pragma unroll
  for (int off = 1; off < 16; off <<= 1)
#pragma unroll
    for (int t = 0; t < 2; ++t)
#pragma unroll
      for (int r = 0; r < 4; ++r) li[t][r] += __shfl_xor(li[t][r], off);

#pragma unroll
  for (int t = 0; t < 2; ++t) {
    uint16_t* ob = O + ((long)(b * 2048 + qbase + t * 16)) * 2048 + h * 128;
    float inv_l[4];
#pragma unroll
    for (int r = 0; r < 4; ++r) inv_l[r] = 1.0f / li[t][r];
#pragma unroll
    for (int nt = 0; nt < 8; ++nt)
#pragma unroll
      for (int r = 0; r < 4; ++r)
        ob[(long)(quad * 4 + r) * 2048 + nt * 16 + r16] = f2bf(oacc[t][nt][r] * inv_l[r]);
  }
}

extern "C" void kernel_launch(void* const* d_in, const int* in_sizes, int n_in,
                              void* d_out, int out_size, void* d_ws, size_t ws_size,
                              hipStream_t stream) {
  const float* x   = (const float*)d_in[0];
  const float* enc = (const float*)d_in[1];
  const int*   msk = (const int*)d_in[2];
  const float* Wq  = (const float*)d_in[3];
  const float* Wk  = (const float*)d_in[4];
  const float* Wv  = (const float*)d_in[5];
  const float* Wo  = (const float*)d_in[6];
  float* out = (float*)d_out;

  const long NELT = 8L * 1024 * 1024;  // 4096 x 2048
  const long WELT = 4L * 1024 * 1024;  // 2048 x 2048
  uint16_t* Qb   = (uint16_t*)d_ws;
  uint16_t* Kb   = Qb + NELT;
  uint16_t* Vtb  = Kb + NELT;   // V GEMM writes transposed directly
  uint16_t* xb   = Vtb + NELT;
  uint16_t* encb = xb + NELT;
  uint16_t* Wb   = encb + NELT;
  uint16_t* Ob   = xb;  // x dead after Q-GEMM; reuse for attention output

  const dim3 gb(16, 32);  // N/128, M/128
  const int CB_ACT = (int)(NELT / 2048);
  const int CB_W   = (int)(WELT / 2048);

  convert_f32_bf16<<<CB_ACT, 256, 0, stream>>>(x, xb);
  convert_f32_bf16<<<CB_W, 256, 0, stream>>>(Wq, Wb);
  gemm_bt<EPI_ROPE><<<gb, 256, 0, stream>>>(xb, Wb, Qb, 4096, 2048, 2048);

  convert_f32_bf16<<<CB_ACT, 256, 0, stream>>>(enc, encb);
  convert_f32_bf16<<<CB_W, 256, 0, stream>>>(Wk, Wb);
  gemm_bt<EPI_ROPE><<<gb, 256, 0, stream>>>(encb, Wb, Kb, 4096, 2048, 2048);

  convert_f32_bf16<<<CB_W, 256, 0, stream>>>(Wv, Wb);
  gemm_bt<EPI_VT><<<gb, 256, 0, stream>>>(encb, Wb, Vtb, 4096, 2048, 2048);

  attn_kernel<<<dim3(16, 16, 2), 256, 0, stream>>>(Qb, Kb, Vtb, msk, Ob);

  convert_f32_bf16<<<CB_W, 256, 0, stream>>>(Wo, Wb);
  gemm_bt<EPI_F32><<<gb, 256, 0, stream>>>(Ob, Wb, out, 4096, 2048, 2048);
}

// Round 6
// 489.027 us; speedup vs baseline: 3.2727x; 1.1645x over previous
//
#include <hip/hip_runtime.h>
#include <stdint.h>

// B=2, SQ=SK=2048, HIDDEN=2048, HEADS=16, HEAD_DIM=128.
// DTYPE MODEL (verified): inputs fp32, mask int32, OUTPUT fp32. Internal bf16 MFMA.
// Round 6: attn K-loop restructured — double-buffered 32-key tiles with ONE barrier
// per iter and cross-barrier glds prefetch (latency-bound fix; r5 showed 11.5% occ,
// no pipe saturated). Q pre-scaled in GEMM epilogue; mask as additive float bias
// (exp2(-inf)=0); cheap round-half-up P pack.

#define LOG2E 1.44269504088896340736f
#define INV2PI 0.15915494309189535f

typedef __attribute__((ext_vector_type(8))) short bf16x8;
typedef __attribute__((ext_vector_type(8))) uint16_t u16x8;
typedef __attribute__((ext_vector_type(4))) uint16_t u16x4;
typedef __attribute__((ext_vector_type(4))) float f32x4;

__device__ __forceinline__ uint16_t f2bf(float f) {
  union { float f; uint32_t i; } v; v.f = f;
  uint32_t x = v.i;
  return (uint16_t)((x + 0x7fffu + ((x >> 16) & 1u)) >> 16);  // RTN-even
}
__device__ __forceinline__ uint32_t f_as_u(float f) { union { float f; uint32_t u; } v; v.f = f; return v.u; }
__device__ __forceinline__ float u_as_f(uint32_t u) { union { uint32_t u; float f; } v; v.u = u; return v.f; }
__device__ __forceinline__ void glds16(const void* g, void* l) {
  __builtin_amdgcn_global_load_lds((const __attribute__((address_space(1))) void*)g,
                                   (__attribute__((address_space(3))) void*)l, 16, 0, 0);
}

// fp32 -> bf16, 8 elems/thread, exact grid (n % 2048 == 0).
__global__ __launch_bounds__(256) void convert_f32_bf16(const float* __restrict__ in,
                                                        uint16_t* __restrict__ out) {
  const long i = ((long)blockIdx.x * 256 + threadIdx.x) * 8;
  const f32x4 a = *(const f32x4*)(in + i);
  const f32x4 b = *(const f32x4*)(in + i + 4);
  u16x8 o;
#pragma unroll
  for (int j = 0; j < 4; ++j) { o[j] = f2bf(a[j]); o[4 + j] = f2bf(b[j]); }
  *(u16x8*)(out + i) = o;
}

// mask int -> additive softmax bias float (0 or -inf). 4096 elems.
__global__ __launch_bounds__(256) void mask_bias(const int* __restrict__ m,
                                                 float* __restrict__ bias) {
  const int i = blockIdx.x * 256 + threadIdx.x;
  bias[i] = m[i] ? 0.0f : -__builtin_inff();
}

// Epilogue modes
#define EPI_ROPE 0  // bf16 out with RoPE applied, scaled by oscale (Q,K GEMMs)
#define EPI_VT   1  // bf16 out transposed to Vt[(b*16+h)*128+d][s] (V GEMM)
#define EPI_F32  2  // fp32 out (final projection)

// C[m][n] = sum_k A[m][k] * W[n][k];  m97 structure, 128x128 tile, BK=32.
template <int MODE>
__global__ __launch_bounds__(256) void gemm_bt(const uint16_t* __restrict__ A,
                                               const uint16_t* __restrict__ W,
                                               void* __restrict__ Cv,
                                               int M, int N, int K, float oscale) {
  __shared__ __align__(16) uint16_t As[128 * 32];
  __shared__ __align__(16) uint16_t Bs[128 * 32];
  const int tid = threadIdx.x;
  const int lane = tid & 63;
  const int w = tid >> 6;
  const int r16 = lane & 15, quad = lane >> 4;
  const int m0 = blockIdx.y * 128, n0 = blockIdx.x * 128;
  const int wm = (w >> 1) * 64, wn = (w & 1) * 64;
  f32x4 acc[4][4] = {};
  const int srow = 32 * w + (lane >> 2);
  const int scol = (lane & 3) * 8;
  const uint16_t* Ag = A + (long)(m0 + srow) * K + scol;
  const uint16_t* Wg = W + (long)(n0 + srow) * K + scol;
  uint16_t* AsW = As + 2 * w * 512;
  uint16_t* BsW = Bs + 2 * w * 512;
  for (int k0 = 0; k0 < K; k0 += 32) {
    glds16(Ag + k0, AsW);
    glds16(Ag + k0 + (long)16 * K, AsW + 512);
    glds16(Wg + k0, BsW);
    glds16(Wg + k0 + (long)16 * K, BsW + 512);
    __syncthreads();
    bf16x8 af[4], bfr[4];
#pragma unroll
    for (int mt = 0; mt < 4; ++mt)
      af[mt] = *(const bf16x8*)(As + (wm + mt * 16 + r16) * 32 + quad * 8);
#pragma unroll
    for (int nt = 0; nt < 4; ++nt)
      bfr[nt] = *(const bf16x8*)(Bs + (wn + nt * 16 + r16) * 32 + quad * 8);
#pragma unroll
    for (int mt = 0; mt < 4; ++mt)
#pragma unroll
      for (int nt = 0; nt < 4; ++nt)
        acc[mt][nt] = __builtin_amdgcn_mfma_f32_16x16x32_bf16(af[mt], bfr[nt], acc[mt][nt], 0, 0, 0);
    __syncthreads();
  }

#pragma unroll
  for (int mt = 0; mt < 4; ++mt)
#pragma unroll
    for (int nt = 0; nt < 4; ++nt) {
      const int col = n0 + wn + nt * 16 + r16;
      const int rowbase = m0 + wm + mt * 16 + quad * 4;
      if constexpr (MODE == EPI_F32) {
        float* C = (float*)Cv;
#pragma unroll
        for (int r = 0; r < 4; ++r)
          C[(long)(rowbase + r) * N + col] = acc[mt][nt][r];
      } else if constexpr (MODE == EPI_ROPE) {
        // RoPE via inline v_exp/v_fract/v_sin/v_cos (no libcalls); pair in lane^1.
        uint16_t* C = (uint16_t*)Cv;
        const int f = (col >> 1) & 63;
        const float inv = __builtin_amdgcn_exp2f((float)f * (-13.287712379549449f / 64.0f));
        const float sgn = (col & 1) ? 1.0f : -1.0f;
#pragma unroll
        for (int r = 0; r < 4; ++r) {
          const float val = acc[mt][nt][r];
          const float partner = __shfl_xor(val, 1);
          const int s = (rowbase + r) & 2047;
          const float rev = __builtin_amdgcn_fractf((float)s * inv * INV2PI);
          const float sn = __builtin_amdgcn_sinf(rev);
          const float cs = __builtin_amdgcn_cosf(rev);
          C[(long)(rowbase + r) * N + col] = f2bf((val * cs + sgn * partner * sn) * oscale);
        }
      } else {  // EPI_VT
        uint16_t* Vt = (uint16_t*)Cv;
        const int h = col >> 7, d = col & 127;
        const int b = rowbase >> 11, s = rowbase & 2047;
        u16x4 pk;
#pragma unroll
        for (int r = 0; r < 4; ++r) pk[r] = f2bf(acc[mt][nt][r]);
        *(u16x4*)(Vt + (long)((b * 16 + h) * 128 + d) * 2048 + s) = pk;
      }
    }
}

// Flash attention v4. Block = (b, h, 128 q) = 4 waves x 32 q. 32-key tiles,
// double-buffered staging, ONE barrier/iter, cross-barrier prefetch.
// LDS: Ks 2x8K + Vts 2x8K + Ps 4x2560 = 43008 B. Q arrives pre-scaled by scale*log2e.
__global__ __launch_bounds__(256) void attn_kernel(const uint16_t* __restrict__ Q,
                                                   const uint16_t* __restrict__ K,
                                                   const uint16_t* __restrict__ Vt,
                                                   const float* __restrict__ bias,
                                                   uint16_t* __restrict__ O) {
  __shared__ __align__(16) uint16_t Ks[2][32 * 128];   // [key][chunk16 ^ (key&7)]
  __shared__ __align__(16) uint16_t Vts[2][128 * 32];  // [dim][keychunk ^ (dim&3)]
  __shared__ __align__(16) uint16_t Ps[4][32 * 40];    // per-wave P, stride 40 (pad)
  const int tid = threadIdx.x;
  const int lane = tid & 63;
  const int w = tid >> 6;
  const int r16 = lane & 15, quad = lane >> 4;
  const int h = blockIdx.y, b = blockIdx.z;
  const int qbase = blockIdx.x * 128 + w * 32;

  // Q fragments (pre-scaled)
  bf16x8 qf[2][4];
#pragma unroll
  for (int t = 0; t < 2; ++t) {
    const uint16_t* qb = Q + ((long)(b * 2048 + qbase + t * 16 + r16)) * 2048 + h * 128 + quad * 8;
#pragma unroll
    for (int c = 0; c < 4; ++c) qf[t][c] = *(const bf16x8*)(qb + c * 32);
  }
  f32x4 oacc[2][8] = {};
  float li[2][4] = {};

  uint16_t* PsW = &Ps[w][0];
  const float* brow = bias + b * 2048;

  // staging source pointers (advance as tiles are issued)
  const int key0[2] = {8 * w + quad, 8 * w + 4 + quad};
  const uint16_t* kg[2];
  const uint16_t* vg[2];
#pragma unroll
  for (int i = 0; i < 2; ++i) {
    kg[i] = K + ((long)(b * 2048 + key0[i])) * 2048 + h * 128 + 8 * (r16 ^ ((4 * i + quad) & 7));
    const int dim = 32 * w + 16 * i + (lane >> 2);
    vg[i] = Vt + ((long)((b * 16 + h) * 128 + dim)) * 2048 + 8 * ((lane & 3) ^ ((lane >> 2) & 3));
  }

  // prologue: stage tile 0 into parity 0; prefetch bias for tile 0
#pragma unroll
  for (int i = 0; i < 2; ++i) {
    glds16(kg[i], &Ks[0][(2 * w + i) * 512]);
    glds16(vg[i], &Vts[0][(2 * w + i) * 512]);
    kg[i] += 32 * 2048;
    vg[i] += 32;
  }
  float bn0 = brow[r16], bn1 = brow[16 + r16];

  auto body = [&](int k0, const uint16_t* Kc, const uint16_t* Vc,
                  uint16_t* Kn, uint16_t* Vn, bool pf) {
    __syncthreads();  // tile k0 staged (vmcnt drained), prev compute done
    const float bc0 = bn0, bc1 = bn1;
    if (pf) {
#pragma unroll
      for (int i = 0; i < 2; ++i) {
        glds16(kg[i], Kn + (2 * w + i) * 512);
        glds16(vg[i], Vn + (2 * w + i) * 512);
        kg[i] += 32 * 2048;
        vg[i] += 32;
      }
      bn0 = brow[k0 + 32 + r16];       // consumed after next barrier: zero-stall
      bn1 = brow[k0 + 48 + r16];
    }
    // S = Q K^T, p = exp2(s + bias), pack round-half-up, per-lane l
#pragma unroll
    for (int ct = 0; ct < 2; ++ct) {
      const int key = ct * 16 + r16;
      const int kb = key & 7;
      bf16x8 kf[4];
#pragma unroll
      for (int c = 0; c < 4; ++c)
        kf[c] = *(const bf16x8*)(Kc + key * 128 + ((4 * c + quad) ^ kb) * 8);
      const float bv = ct ? bc1 : bc0;
      const int pc = ct * 2 + (r16 >> 3);
#pragma unroll
      for (int t = 0; t < 2; ++t) {
        f32x4 s = {};
#pragma unroll
        for (int c = 0; c < 4; ++c)
          s = __builtin_amdgcn_mfma_f32_16x16x32_bf16(qf[t][c], kf[c], s, 0, 0, 0);
#pragma unroll
        for (int r = 0; r < 4; ++r) {
          const float p = __builtin_amdgcn_exp2f(s[r] + bv);
          const uint32_t pb = f_as_u(p) + 0x8000u;  // round-half-up to bf16
          const int row = t * 16 + quad * 4 + r;    // row&3 == r
          PsW[row * 40 + ((pc ^ r) << 3) + (r16 & 7)] = (uint16_t)(pb >> 16);
          li[t][r] += u_as_f(pb & 0xffff0000u);     // sum the rounded value
        }
      }
    }
    // O += P V
    bf16x8 pa[2];
#pragma unroll
    for (int t = 0; t < 2; ++t)
      pa[t] = *(const bf16x8*)(PsW + (t * 16 + r16) * 40 + ((quad ^ (r16 & 3)) << 3));
#pragma unroll
    for (int nt = 0; nt < 8; ++nt) {
      const int dim = nt * 16 + r16;
      bf16x8 vf = *(const bf16x8*)(Vc + dim * 32 + ((quad ^ (dim & 3)) << 3));
#pragma unroll
      for (int t = 0; t < 2; ++t)
        oacc[t][nt] = __builtin_amdgcn_mfma_f32_16x16x32_bf16(pa[t], vf, oacc[t][nt], 0, 0, 0);
    }
  };

  for (int kt2 = 0; kt2 < 32; ++kt2) {
    body(64 * kt2,      &Ks[0][0], &Vts[0][0], &Ks[1][0], &Vts[1][0], true);
    body(64 * kt2 + 32, &Ks[1][0], &Vts[1][0], &Ks[0][0], &Vts[0][0], kt2 < 31);
  }

  // reduce row sums across the 16 key-lanes (fixed-shift softmax)
#pragma unroll
  for (int off = 1; off < 16; off <<= 1)
#pragma unroll
    for (int t = 0; t < 2; ++t)
#pragma unroll
      for (int r = 0; r < 4; ++r) li[t][r] += __shfl_xor(li[t][r], off);

#pragma unroll
  for (int t = 0; t < 2; ++t) {
    uint16_t* ob = O + ((long)(b * 2048 + qbase + t * 16)) * 2048 + h * 128;
    float inv_l[4];
#pragma unroll
    for (int r = 0; r < 4; ++r) inv_l[r] = 1.0f / li[t][r];
#pragma unroll
    for (int nt = 0; nt < 8; ++nt)
#pragma unroll
      for (int r = 0; r < 4; ++r)
        ob[(long)(quad * 4 + r) * 2048 + nt * 16 + r16] = f2bf(oacc[t][nt][r] * inv_l[r]);
  }
}

extern "C" void kernel_launch(void* const* d_in, const int* in_sizes, int n_in,
                              void* d_out, int out_size, void* d_ws, size_t ws_size,
                              hipStream_t stream) {
  const float* x   = (const float*)d_in[0];
  const float* enc = (const float*)d_in[1];
  const int*   msk = (const int*)d_in[2];
  const float* Wq  = (const float*)d_in[3];
  const float* Wk  = (const float*)d_in[4];
  const float* Wv  = (const float*)d_in[5];
  const float* Wo  = (const float*)d_in[6];
  float* out = (float*)d_out;

  const long NELT = 8L * 1024 * 1024;  // 4096 x 2048
  const long WELT = 4L * 1024 * 1024;  // 2048 x 2048
  uint16_t* Qb   = (uint16_t*)d_ws;
  uint16_t* Kb   = Qb + NELT;
  uint16_t* Vtb  = Kb + NELT;   // V GEMM writes transposed directly
  uint16_t* xb   = Vtb + NELT;
  uint16_t* encb = xb + NELT;
  uint16_t* Wb   = encb + NELT;
  uint16_t* Ob   = xb;                 // x dead after Q-GEMM
  float*    biasb = (float*)encb;      // enc dead after V-GEMM

  const float cs_exp = 0.088388347648318447f * LOG2E;  // folded into Q

  const dim3 gb(16, 32);  // N/128, M/128
  const int CB_ACT = (int)(NELT / 2048);
  const int CB_W   = (int)(WELT / 2048);

  convert_f32_bf16<<<CB_ACT, 256, 0, stream>>>(x, xb);
  convert_f32_bf16<<<CB_W, 256, 0, stream>>>(Wq, Wb);
  gemm_bt<EPI_ROPE><<<gb, 256, 0, stream>>>(xb, Wb, Qb, 4096, 2048, 2048, cs_exp);

  convert_f32_bf16<<<CB_ACT, 256, 0, stream>>>(enc, encb);
  convert_f32_bf16<<<CB_W, 256, 0, stream>>>(Wk, Wb);
  gemm_bt<EPI_ROPE><<<gb, 256, 0, stream>>>(encb, Wb, Kb, 4096, 2048, 2048, 1.0f);

  convert_f32_bf16<<<CB_W, 256, 0, stream>>>(Wv, Wb);
  gemm_bt<EPI_VT><<<gb, 256, 0, stream>>>(encb, Wb, Vtb, 4096, 2048, 2048, 1.0f);

  mask_bias<<<16, 256, 0, stream>>>(msk, biasb);

  attn_kernel<<<dim3(16, 16, 2), 256, 0, stream>>>(Qb, Kb, Vtb, biasb, Ob);

  convert_f32_bf16<<<CB_W, 256, 0, stream>>>(Wo, Wb);
  gemm_bt<EPI_F32><<<gb, 256, 0, stream>>>(Ob, Wb, out, 4096, 2048, 2048, 1.0f);
}

// Round 7
// 484.538 us; speedup vs baseline: 3.3030x; 1.0093x over previous
//
#include <hip/hip_runtime.h>
#include <stdint.h>

// B=2, SQ=SK=2048, HIDDEN=2048, HEADS=16, HEAD_DIM=128.
// DTYPE MODEL (verified): inputs fp32, mask int32, OUTPUT fp32. Internal bf16 MFMA.
// Round 7: GEMM K-loop gets the round-6 treatment — double-buffered LDS, ONE
// barrier/iter, cross-barrier glds prefetch (r6 GEMMs were 82us = 20% of MFMA
// ceiling, latency-bound at the vmcnt(0)-before-barrier drain). K+V GEMMs merged
// into one N=4096 dispatch (4 blocks/CU) with per-half epilogue.

#define LOG2E 1.44269504088896340736f
#define INV2PI 0.15915494309189535f

typedef __attribute__((ext_vector_type(8))) short bf16x8;
typedef __attribute__((ext_vector_type(8))) uint16_t u16x8;
typedef __attribute__((ext_vector_type(4))) uint16_t u16x4;
typedef __attribute__((ext_vector_type(4))) float f32x4;

__device__ __forceinline__ uint16_t f2bf(float f) {
  union { float f; uint32_t i; } v; v.f = f;
  uint32_t x = v.i;
  return (uint16_t)((x + 0x7fffu + ((x >> 16) & 1u)) >> 16);  // RTN-even
}
__device__ __forceinline__ uint32_t f_as_u(float f) { union { float f; uint32_t u; } v; v.f = f; return v.u; }
__device__ __forceinline__ float u_as_f(uint32_t u) { union { uint32_t u; float f; } v; v.u = u; return v.f; }
__device__ __forceinline__ void glds16(const void* g, void* l) {
  __builtin_amdgcn_global_load_lds((const __attribute__((address_space(1))) void*)g,
                                   (__attribute__((address_space(3))) void*)l, 16, 0, 0);
}

// fp32 -> bf16, 8 elems/thread, exact grid (n % 2048 == 0).
__global__ __launch_bounds__(256) void convert_f32_bf16(const float* __restrict__ in,
                                                        uint16_t* __restrict__ out) {
  const long i = ((long)blockIdx.x * 256 + threadIdx.x) * 8;
  const f32x4 a = *(const f32x4*)(in + i);
  const f32x4 b = *(const f32x4*)(in + i + 4);
  u16x8 o;
#pragma unroll
  for (int j = 0; j < 4; ++j) { o[j] = f2bf(a[j]); o[4 + j] = f2bf(b[j]); }
  *(u16x8*)(out + i) = o;
}

// mask int -> additive softmax bias float (0 or -inf). 4096 elems.
__global__ __launch_bounds__(256) void mask_bias(const int* __restrict__ m,
                                                 float* __restrict__ bias) {
  const int i = blockIdx.x * 256 + threadIdx.x;
  bias[i] = m[i] ? 0.0f : -__builtin_inff();
}

// Epilogue modes
#define EPI_ROPE 0  // bf16 out with RoPE applied, scaled by oscale (Q GEMM)
#define EPI_KV   1  // N=4096 merged: cols<2048 RoPE->C0 (K); cols>=2048 Vt->C1
#define EPI_F32  2  // fp32 out (final projection)

__device__ __forceinline__ void epi_rope_store(uint16_t* C, const f32x4& a, int rowbase,
                                               int col, int N, float oscale) {
  const int f = (col >> 1) & 63;
  const float inv = __builtin_amdgcn_exp2f((float)f * (-13.287712379549449f / 64.0f));
  const float sgn = (col & 1) ? 1.0f : -1.0f;
#pragma unroll
  for (int r = 0; r < 4; ++r) {
    const float val = a[r];
    const float partner = __shfl_xor(val, 1);
    const int s = (rowbase + r) & 2047;
    const float rev = __builtin_amdgcn_fractf((float)s * inv * INV2PI);
    const float sn = __builtin_amdgcn_sinf(rev);
    const float cs = __builtin_amdgcn_cosf(rev);
    C[(long)(rowbase + r) * N + col] = f2bf((val * cs + sgn * partner * sn) * oscale);
  }
}

// C[m][n] = sum_k A[m][k] * W[n][k]; 128x128 tile, BK=32, double-buffered LDS,
// one barrier per K-iter with cross-barrier glds prefetch.
// W rows n<2048 come from W0, n>=2048 from W1 (EPI_KV); others use W0 only.
template <int MODE>
__global__ __launch_bounds__(256) void gemm_bt(const uint16_t* __restrict__ A,
                                               const uint16_t* __restrict__ W0,
                                               const uint16_t* __restrict__ W1,
                                               void* __restrict__ C0v,
                                               void* __restrict__ C1v,
                                               int M, int N, int K, float oscale) {
  __shared__ __align__(16) uint16_t As[2][128 * 32];
  __shared__ __align__(16) uint16_t Bs[2][128 * 32];
  const int tid = threadIdx.x;
  const int lane = tid & 63;
  const int w = tid >> 6;
  const int r16 = lane & 15, quad = lane >> 4;
  const int m0 = blockIdx.y * 128, n0 = blockIdx.x * 128;
  const int wm = (w >> 1) * 64, wn = (w & 1) * 64;
  f32x4 acc[4][4] = {};
  const int srow = 32 * w + (lane >> 2);
  const int scol = (lane & 3) * 8;
  const uint16_t* Wbase = (MODE == EPI_KV && n0 >= 2048) ? W1 + (long)(n0 - 2048) * K
                                                         : W0 + (long)n0 * K;
  const uint16_t* Ag = A + (long)(m0 + srow) * K + scol;
  const uint16_t* Wg = Wbase + (long)srow * K + scol;
  const int co = 2 * w * 512;  // this wave's 1KB-chunk offset within a tile

  // prologue: stage tile 0 into parity 0
  glds16(Ag, &As[0][co]);
  glds16(Ag + (long)16 * K, &As[0][co + 512]);
  glds16(Wg, &Bs[0][co]);
  glds16(Wg + (long)16 * K, &Bs[0][co + 512]);

  auto body = [&](int k1, const uint16_t* Ac, const uint16_t* Bc,
                  uint16_t* An, uint16_t* Bn, bool pf) {
    __syncthreads();  // current tile staged (vmcnt drained at barrier), prev compute done
    if (pf) {
      glds16(Ag + k1, An + co);
      glds16(Ag + k1 + (long)16 * K, An + co + 512);
      glds16(Wg + k1, Bn + co);
      glds16(Wg + k1 + (long)16 * K, Bn + co + 512);
    }
    bf16x8 af[4], bfr[4];
#pragma unroll
    for (int mt = 0; mt < 4; ++mt)
      af[mt] = *(const bf16x8*)(Ac + (wm + mt * 16 + r16) * 32 + quad * 8);
#pragma unroll
    for (int nt = 0; nt < 4; ++nt)
      bfr[nt] = *(const bf16x8*)(Bc + (wn + nt * 16 + r16) * 32 + quad * 8);
#pragma unroll
    for (int mt = 0; mt < 4; ++mt)
#pragma unroll
      for (int nt = 0; nt < 4; ++nt)
        acc[mt][nt] = __builtin_amdgcn_mfma_f32_16x16x32_bf16(af[mt], bfr[nt], acc[mt][nt], 0, 0, 0);
  };

  const int NK2 = K >> 6;  // pairs of 32-wide K tiles
  for (int kk = 0; kk < NK2; ++kk) {
    body((2 * kk + 1) * 32, &As[0][0], &Bs[0][0], &As[1][0], &Bs[1][0], true);
    body((2 * kk + 2) * 32, &As[1][0], &Bs[1][0], &As[0][0], &Bs[0][0], kk < NK2 - 1);
  }

#pragma unroll
  for (int mt = 0; mt < 4; ++mt)
#pragma unroll
    for (int nt = 0; nt < 4; ++nt) {
      const int col = n0 + wn + nt * 16 + r16;
      const int rowbase = m0 + wm + mt * 16 + quad * 4;
      if constexpr (MODE == EPI_F32) {
        float* C = (float*)C0v;
#pragma unroll
        for (int r = 0; r < 4; ++r)
          C[(long)(rowbase + r) * N + col] = acc[mt][nt][r];
      } else if constexpr (MODE == EPI_ROPE) {
        epi_rope_store((uint16_t*)C0v, acc[mt][nt], rowbase, col, N, oscale);
      } else {  // EPI_KV: block-uniform branch on n0
        if (n0 < 2048) {
          epi_rope_store((uint16_t*)C0v, acc[mt][nt], rowbase, col, 2048, 1.0f);
        } else {
          uint16_t* Vt = (uint16_t*)C1v;
          const int c = col - 2048;
          const int h = c >> 7, d = c & 127;
          const int b = rowbase >> 11, s = rowbase & 2047;
          u16x4 pk;
#pragma unroll
          for (int r = 0; r < 4; ++r) pk[r] = f2bf(acc[mt][nt][r]);
          *(u16x4*)(Vt + (long)((b * 16 + h) * 128 + d) * 2048 + s) = pk;
        }
      }
    }
}

// Flash attention v4 (round-6, unchanged). Block = (b, h, 128 q) = 4 waves x 32 q.
// 32-key tiles, double-buffered staging, ONE barrier/iter, cross-barrier prefetch.
// LDS: Ks 2x8K + Vts 2x8K + Ps 4x2560 = 43008 B. Q arrives pre-scaled by scale*log2e.
__global__ __launch_bounds__(256) void attn_kernel(const uint16_t* __restrict__ Q,
                                                   const uint16_t* __restrict__ K,
                                                   const uint16_t* __restrict__ Vt,
                                                   const float* __restrict__ bias,
                                                   uint16_t* __restrict__ O) {
  __shared__ __align__(16) uint16_t Ks[2][32 * 128];   // [key][chunk16 ^ (key&7)]
  __shared__ __align__(16) uint16_t Vts[2][128 * 32];  // [dim][keychunk ^ (dim&3)]
  __shared__ __align__(16) uint16_t Ps[4][32 * 40];    // per-wave P, stride 40 (pad)
  const int tid = threadIdx.x;
  const int lane = tid & 63;
  const int w = tid >> 6;
  const int r16 = lane & 15, quad = lane >> 4;
  const int h = blockIdx.y, b = blockIdx.z;
  const int qbase = blockIdx.x * 128 + w * 32;

  bf16x8 qf[2][4];
#pragma unroll
  for (int t = 0; t < 2; ++t) {
    const uint16_t* qb = Q + ((long)(b * 2048 + qbase + t * 16 + r16)) * 2048 + h * 128 + quad * 8;
#pragma unroll
    for (int c = 0; c < 4; ++c) qf[t][c] = *(const bf16x8*)(qb + c * 32);
  }
  f32x4 oacc[2][8] = {};
  float li[2][4] = {};

  uint16_t* PsW = &Ps[w][0];
  const float* brow = bias + b * 2048;

  const int key0[2] = {8 * w + quad, 8 * w + 4 + quad};
  const uint16_t* kg[2];
  const uint16_t* vg[2];
#pragma unroll
  for (int i = 0; i < 2; ++i) {
    kg[i] = K + ((long)(b * 2048 + key0[i])) * 2048 + h * 128 + 8 * (r16 ^ ((4 * i + quad) & 7));
    const int dim = 32 * w + 16 * i + (lane >> 2);
    vg[i] = Vt + ((long)((b * 16 + h) * 128 + dim)) * 2048 + 8 * ((lane & 3) ^ ((lane >> 2) & 3));
  }

#pragma unroll
  for (int i = 0; i < 2; ++i) {
    glds16(kg[i], &Ks[0][(2 * w + i) * 512]);
    glds16(vg[i], &Vts[0][(2 * w + i) * 512]);
    kg[i] += 32 * 2048;
    vg[i] += 32;
  }
  float bn0 = brow[r16], bn1 = brow[16 + r16];

  auto body = [&](int k0, const uint16_t* Kc, const uint16_t* Vc,
                  uint16_t* Kn, uint16_t* Vn, bool pf) {
    __syncthreads();
    const float bc0 = bn0, bc1 = bn1;
    if (pf) {
#pragma unroll
      for (int i = 0; i < 2; ++i) {
        glds16(kg[i], Kn + (2 * w + i) * 512);
        glds16(vg[i], Vn + (2 * w + i) * 512);
        kg[i] += 32 * 2048;
        vg[i] += 32;
      }
      bn0 = brow[k0 + 32 + r16];
      bn1 = brow[k0 + 48 + r16];
    }
#pragma unroll
    for (int ct = 0; ct < 2; ++ct) {
      const int key = ct * 16 + r16;
      const int kb = key & 7;
      bf16x8 kf[4];
#pragma unroll
      for (int c = 0; c < 4; ++c)
        kf[c] = *(const bf16x8*)(Kc + key * 128 + ((4 * c + quad) ^ kb) * 8);
      const float bv = ct ? bc1 : bc0;
      const int pc = ct * 2 + (r16 >> 3);
#pragma unroll
      for (int t = 0; t < 2; ++t) {
        f32x4 s = {};
#pragma unroll
        for (int c = 0; c < 4; ++c)
          s = __builtin_amdgcn_mfma_f32_16x16x32_bf16(qf[t][c], kf[c], s, 0, 0, 0);
#pragma unroll
        for (int r = 0; r < 4; ++r) {
          const float p = __builtin_amdgcn_exp2f(s[r] + bv);
          const uint32_t pb = f_as_u(p) + 0x8000u;  // round-half-up to bf16
          const int row = t * 16 + quad * 4 + r;    // row&3 == r
          PsW[row * 40 + ((pc ^ r) << 3) + (r16 & 7)] = (uint16_t)(pb >> 16);
          li[t][r] += u_as_f(pb & 0xffff0000u);
        }
      }
    }
    bf16x8 pa[2];
#pragma unroll
    for (int t = 0; t < 2; ++t)
      pa[t] = *(const bf16x8*)(PsW + (t * 16 + r16) * 40 + ((quad ^ (r16 & 3)) << 3));
#pragma unroll
    for (int nt = 0; nt < 8; ++nt) {
      const int dim = nt * 16 + r16;
      bf16x8 vf = *(const bf16x8*)(Vc + dim * 32 + ((quad ^ (dim & 3)) << 3));
#pragma unroll
      for (int t = 0; t < 2; ++t)
        oacc[t][nt] = __builtin_amdgcn_mfma_f32_16x16x32_bf16(pa[t], vf, oacc[t][nt], 0, 0, 0);
    }
  };

  for (int kt2 = 0; kt2 < 32; ++kt2) {
    body(64 * kt2,      &Ks[0][0], &Vts[0][0], &Ks[1][0], &Vts[1][0], true);
    body(64 * kt2 + 32, &Ks[1][0], &Vts[1][0], &Ks[0][0], &Vts[0][0], kt2 < 31);
  }

#pragma unroll
  for (int off = 1; off < 16; off <<= 1)
#pragma unroll
    for (int t = 0; t < 2; ++t)
#pragma unroll
      for (int r = 0; r < 4; ++r) li[t][r] += __shfl_xor(li[t][r], off);

#pragma unroll
  for (int t = 0; t < 2; ++t) {
    uint16_t* ob = O + ((long)(b * 2048 + qbase + t * 16)) * 2048 + h * 128;
    float inv_l[4];
#pragma unroll
    for (int r = 0; r < 4; ++r) inv_l[r] = 1.0f / li[t][r];
#pragma unroll
    for (int nt = 0; nt < 8; ++nt)
#pragma unroll
      for (int r = 0; r < 4; ++r)
        ob[(long)(quad * 4 + r) * 2048 + nt * 16 + r16] = f2bf(oacc[t][nt][r] * inv_l[r]);
  }
}

extern "C" void kernel_launch(void* const* d_in, const int* in_sizes, int n_in,
                              void* d_out, int out_size, void* d_ws, size_t ws_size,
                              hipStream_t stream) {
  const float* x   = (const float*)d_in[0];
  const float* enc = (const float*)d_in[1];
  const int*   msk = (const int*)d_in[2];
  const float* Wq  = (const float*)d_in[3];
  const float* Wk  = (const float*)d_in[4];
  const float* Wv  = (const float*)d_in[5];
  const float* Wo  = (const float*)d_in[6];
  float* out = (float*)d_out;

  const long NELT = 8L * 1024 * 1024;  // 4096 x 2048
  const long WELT = 4L * 1024 * 1024;  // 2048 x 2048
  uint16_t* Qb   = (uint16_t*)d_ws;
  uint16_t* Kb   = Qb + NELT;
  uint16_t* Vtb  = Kb + NELT;   // KV GEMM writes V transposed directly
  uint16_t* xb   = Vtb + NELT;
  uint16_t* encb = xb + NELT;
  uint16_t* Wb   = encb + NELT;
  uint16_t* Wvb  = xb;                 // x dead after Q-GEMM; holds Wv for KV GEMM
  uint16_t* Ob   = xb;                 // Wv copy dead after KV GEMM
  float*    biasb = (float*)encb;      // enc dead after KV GEMM

  const float cs_exp = 0.088388347648318447f * LOG2E;  // folded into Q

  const int CB_ACT = (int)(NELT / 2048);
  const int CB_W   = (int)(WELT / 2048);

  convert_f32_bf16<<<CB_ACT, 256, 0, stream>>>(x, xb);
  convert_f32_bf16<<<CB_W, 256, 0, stream>>>(Wq, Wb);
  gemm_bt<EPI_ROPE><<<dim3(16, 32), 256, 0, stream>>>(xb, Wb, nullptr, Qb, nullptr,
                                                      4096, 2048, 2048, cs_exp);

  convert_f32_bf16<<<CB_ACT, 256, 0, stream>>>(enc, encb);
  convert_f32_bf16<<<CB_W, 256, 0, stream>>>(Wk, Wb);
  convert_f32_bf16<<<CB_W, 256, 0, stream>>>(Wv, Wvb);
  gemm_bt<EPI_KV><<<dim3(32, 32), 256, 0, stream>>>(encb, Wb, Wvb, Kb, Vtb,
                                                    4096, 4096, 2048, 1.0f);

  mask_bias<<<16, 256, 0, stream>>>(msk, biasb);

  attn_kernel<<<dim3(16, 16, 2), 256, 0, stream>>>(Qb, Kb, Vtb, biasb, Ob);

  convert_f32_bf16<<<CB_W, 256, 0, stream>>>(Wo, Wb);
  gemm_bt<EPI_F32><<<dim3(16, 32), 256, 0, stream>>>(Ob, Wb, nullptr, out, nullptr,
                                                     4096, 2048, 2048, 1.0f);
}

// Round 8
// 478.869 us; speedup vs baseline: 3.3421x; 1.0118x over previous
//
#include <hip/hip_runtime.h>
#include <stdint.h>

// B=2, SQ=SK=2048, HIDDEN=2048, HEADS=16, HEAD_DIM=128.
// DTYPE MODEL (verified): inputs fp32, mask int32, OUTPUT fp32. Internal bf16 MFMA.
// Round 8: single QKV mega-GEMM (N=6144, 1536 blocks = 6/CU — r7 showed the merged
// KV's 4-blocks/CU grid hit 1127 TF vs 763 for 2-blocks/CU N=2048 GEMMs).
// Workspace: xb/encb live in d_out (scratch until final write); W4 = all 4 weights
// contiguous; Ob aliases dead Wq/Wk. Peak ws = 80 MiB (< proven 88).

#define LOG2E 1.44269504088896340736f
#define INV2PI 0.15915494309189535f

typedef __attribute__((ext_vector_type(8))) short bf16x8;
typedef __attribute__((ext_vector_type(8))) uint16_t u16x8;
typedef __attribute__((ext_vector_type(4))) uint16_t u16x4;
typedef __attribute__((ext_vector_type(4))) float f32x4;

__device__ __forceinline__ uint16_t f2bf(float f) {
  union { float f; uint32_t i; } v; v.f = f;
  uint32_t x = v.i;
  return (uint16_t)((x + 0x7fffu + ((x >> 16) & 1u)) >> 16);  // RTN-even
}
__device__ __forceinline__ uint32_t f_as_u(float f) { union { float f; uint32_t u; } v; v.f = f; return v.u; }
__device__ __forceinline__ float u_as_f(uint32_t u) { union { uint32_t u; float f; } v; v.u = u; return v.f; }
__device__ __forceinline__ void glds16(const void* g, void* l) {
  __builtin_amdgcn_global_load_lds((const __attribute__((address_space(1))) void*)g,
                                   (__attribute__((address_space(3))) void*)l, 16, 0, 0);
}

// fp32 -> bf16, 8 elems/thread, exact grid (n % 2048 == 0).
__global__ __launch_bounds__(256) void convert_f32_bf16(const float* __restrict__ in,
                                                        uint16_t* __restrict__ out) {
  const long i = ((long)blockIdx.x * 256 + threadIdx.x) * 8;
  const f32x4 a = *(const f32x4*)(in + i);
  const f32x4 b = *(const f32x4*)(in + i + 4);
  u16x8 o;
#pragma unroll
  for (int j = 0; j < 4; ++j) { o[j] = f2bf(a[j]); o[4 + j] = f2bf(b[j]); }
  *(u16x8*)(out + i) = o;
}

// All four weights -> one contiguous bf16 buffer W4 = [Wq|Wk|Wv|Wo], 4M elems each.
__global__ __launch_bounds__(256) void convert_w4(const float* __restrict__ Wq,
                                                  const float* __restrict__ Wk,
                                                  const float* __restrict__ Wv,
                                                  const float* __restrict__ Wo,
                                                  uint16_t* __restrict__ W4) {
  const int blk = blockIdx.x;        // 8192 blocks, 2048 per section
  const int sec = blk >> 11;
  const long off = ((long)(blk & 2047) * 256 + threadIdx.x) * 8;
  const float* src = (sec == 0) ? Wq : (sec == 1) ? Wk : (sec == 2) ? Wv : Wo;
  const f32x4 a = *(const f32x4*)(src + off);
  const f32x4 b = *(const f32x4*)(src + off + 4);
  u16x8 o;
#pragma unroll
  for (int j = 0; j < 4; ++j) { o[j] = f2bf(a[j]); o[4 + j] = f2bf(b[j]); }
  *(u16x8*)(W4 + (long)sec * 4194304 + off) = o;
}

// mask int -> additive softmax bias float (0 or -inf). 4096 elems.
__global__ __launch_bounds__(256) void mask_bias(const int* __restrict__ m,
                                                 float* __restrict__ bias) {
  const int i = blockIdx.x * 256 + threadIdx.x;
  bias[i] = m[i] ? 0.0f : -__builtin_inff();
}

// Epilogue modes
#define EPI_QKV 0  // N=6144: n<2048 RoPE*scale->Q; <4096 RoPE->K; else Vt
#define EPI_F32 1  // fp32 out (final projection)

// c is the section-local column; C has row stride 2048.
__device__ __forceinline__ void epi_rope_store(uint16_t* C, const f32x4& a, int rowbase,
                                               int c, float oscale) {
  const int f = (c >> 1) & 63;
  const float inv = __builtin_amdgcn_exp2f((float)f * (-13.287712379549449f / 64.0f));
  const float sgn = (c & 1) ? 1.0f : -1.0f;
#pragma unroll
  for (int r = 0; r < 4; ++r) {
    const float val = a[r];
    const float partner = __shfl_xor(val, 1);
    const int s = (rowbase + r) & 2047;
    const float rev = __builtin_amdgcn_fractf((float)s * inv * INV2PI);
    const float sn = __builtin_amdgcn_sinf(rev);
    const float cs = __builtin_amdgcn_cosf(rev);
    C[(long)(rowbase + r) * 2048 + c] = f2bf((val * cs + sgn * partner * sn) * oscale);
  }
}

// C[m][n] = sum_k A[m][k] * W[n][k]; 128x128 tile, BK=32, double-buffered LDS,
// one barrier per K-iter with cross-barrier glds prefetch.
// EPI_QKV: A = (n0<2048) ? A0 : A1; W is contiguous over n in [0,6144).
template <int MODE>
__global__ __launch_bounds__(256) void gemm_bt(const uint16_t* __restrict__ A0,
                                               const uint16_t* __restrict__ A1,
                                               const uint16_t* __restrict__ W,
                                               void* __restrict__ C0v,
                                               void* __restrict__ C1v,
                                               void* __restrict__ C2v,
                                               int M, int N, int K, float oscale) {
  __shared__ __align__(16) uint16_t As[2][128 * 32];
  __shared__ __align__(16) uint16_t Bs[2][128 * 32];
  const int tid = threadIdx.x;
  const int lane = tid & 63;
  const int w = tid >> 6;
  const int r16 = lane & 15, quad = lane >> 4;
  const int m0 = blockIdx.y * 128, n0 = blockIdx.x * 128;
  const int wm = (w >> 1) * 64, wn = (w & 1) * 64;
  f32x4 acc[4][4] = {};
  const int srow = 32 * w + (lane >> 2);
  const int scol = (lane & 3) * 8;
  const uint16_t* A = (MODE == EPI_QKV && n0 >= 2048) ? A1 : A0;
  const uint16_t* Ag = A + (long)(m0 + srow) * K + scol;
  const uint16_t* Wg = W + (long)(n0 + srow) * K + scol;
  const int co = 2 * w * 512;  // this wave's 1KB-chunk offset within a tile

  // prologue: stage tile 0 into parity 0
  glds16(Ag, &As[0][co]);
  glds16(Ag + (long)16 * K, &As[0][co + 512]);
  glds16(Wg, &Bs[0][co]);
  glds16(Wg + (long)16 * K, &Bs[0][co + 512]);

  auto body = [&](int k1, const uint16_t* Ac, const uint16_t* Bc,
                  uint16_t* An, uint16_t* Bn, bool pf) {
    __syncthreads();  // current tile staged (vmcnt drained at barrier), prev compute done
    if (pf) {
      glds16(Ag + k1, An + co);
      glds16(Ag + k1 + (long)16 * K, An + co + 512);
      glds16(Wg + k1, Bn + co);
      glds16(Wg + k1 + (long)16 * K, Bn + co + 512);
    }
    bf16x8 af[4], bfr[4];
#pragma unroll
    for (int mt = 0; mt < 4; ++mt)
      af[mt] = *(const bf16x8*)(Ac + (wm + mt * 16 + r16) * 32 + quad * 8);
#pragma unroll
    for (int nt = 0; nt < 4; ++nt)
      bfr[nt] = *(const bf16x8*)(Bc + (wn + nt * 16 + r16) * 32 + quad * 8);
#pragma unroll
    for (int mt = 0; mt < 4; ++mt)
#pragma unroll
      for (int nt = 0; nt < 4; ++nt)
        acc[mt][nt] = __builtin_amdgcn_mfma_f32_16x16x32_bf16(af[mt], bfr[nt], acc[mt][nt], 0, 0, 0);
  };

  const int NK2 = K >> 6;  // pairs of 32-wide K tiles
  for (int kk = 0; kk < NK2; ++kk) {
    body((2 * kk + 1) * 32, &As[0][0], &Bs[0][0], &As[1][0], &Bs[1][0], true);
    body((2 * kk + 2) * 32, &As[1][0], &Bs[1][0], &As[0][0], &Bs[0][0], kk < NK2 - 1);
  }

#pragma unroll
  for (int mt = 0; mt < 4; ++mt)
#pragma unroll
    for (int nt = 0; nt < 4; ++nt) {
      const int col = n0 + wn + nt * 16 + r16;
      const int rowbase = m0 + wm + mt * 16 + quad * 4;
      if constexpr (MODE == EPI_F32) {
        float* C = (float*)C0v;
#pragma unroll
        for (int r = 0; r < 4; ++r)
          C[(long)(rowbase + r) * N + col] = acc[mt][nt][r];
      } else {  // EPI_QKV: block-uniform branch on n0
        if (n0 < 2048) {
          epi_rope_store((uint16_t*)C0v, acc[mt][nt], rowbase, col, oscale);      // Q
        } else if (n0 < 4096) {
          epi_rope_store((uint16_t*)C1v, acc[mt][nt], rowbase, col - 2048, 1.0f); // K
        } else {
          uint16_t* Vt = (uint16_t*)C2v;
          const int c = col - 4096;
          const int h = c >> 7, d = c & 127;
          const int b = rowbase >> 11, s = rowbase & 2047;
          u16x4 pk;
#pragma unroll
          for (int r = 0; r < 4; ++r) pk[r] = f2bf(acc[mt][nt][r]);
          *(u16x4*)(Vt + (long)((b * 16 + h) * 128 + d) * 2048 + s) = pk;
        }
      }
    }
}

// Flash attention v4 (round-6, unchanged). Block = (b, h, 128 q) = 4 waves x 32 q.
// 32-key tiles, double-buffered staging, ONE barrier/iter, cross-barrier prefetch.
// LDS: Ks 2x8K + Vts 2x8K + Ps 4x2560 = 43008 B. Q arrives pre-scaled by scale*log2e.
__global__ __launch_bounds__(256) void attn_kernel(const uint16_t* __restrict__ Q,
                                                   const uint16_t* __restrict__ K,
                                                   const uint16_t* __restrict__ Vt,
                                                   const float* __restrict__ bias,
                                                   uint16_t* __restrict__ O) {
  __shared__ __align__(16) uint16_t Ks[2][32 * 128];   // [key][chunk16 ^ (key&7)]
  __shared__ __align__(16) uint16_t Vts[2][128 * 32];  // [dim][keychunk ^ (dim&3)]
  __shared__ __align__(16) uint16_t Ps[4][32 * 40];    // per-wave P, stride 40 (pad)
  const int tid = threadIdx.x;
  const int lane = tid & 63;
  const int w = tid >> 6;
  const int r16 = lane & 15, quad = lane >> 4;
  const int h = blockIdx.y, b = blockIdx.z;
  const int qbase = blockIdx.x * 128 + w * 32;

  bf16x8 qf[2][4];
#pragma unroll
  for (int t = 0; t < 2; ++t) {
    const uint16_t* qb = Q + ((long)(b * 2048 + qbase + t * 16 + r16)) * 2048 + h * 128 + quad * 8;
#pragma unroll
    for (int c = 0; c < 4; ++c) qf[t][c] = *(const bf16x8*)(qb + c * 32);
  }
  f32x4 oacc[2][8] = {};
  float li[2][4] = {};

  uint16_t* PsW = &Ps[w][0];
  const float* brow = bias + b * 2048;

  const int key0[2] = {8 * w + quad, 8 * w + 4 + quad};
  const uint16_t* kg[2];
  const uint16_t* vg[2];
#pragma unroll
  for (int i = 0; i < 2; ++i) {
    kg[i] = K + ((long)(b * 2048 + key0[i])) * 2048 + h * 128 + 8 * (r16 ^ ((4 * i + quad) & 7));
    const int dim = 32 * w + 16 * i + (lane >> 2);
    vg[i] = Vt + ((long)((b * 16 + h) * 128 + dim)) * 2048 + 8 * ((lane & 3) ^ ((lane >> 2) & 3));
  }

#pragma unroll
  for (int i = 0; i < 2; ++i) {
    glds16(kg[i], &Ks[0][(2 * w + i) * 512]);
    glds16(vg[i], &Vts[0][(2 * w + i) * 512]);
    kg[i] += 32 * 2048;
    vg[i] += 32;
  }
  float bn0 = brow[r16], bn1 = brow[16 + r16];

  auto body = [&](int k0, const uint16_t* Kc, const uint16_t* Vc,
                  uint16_t* Kn, uint16_t* Vn, bool pf) {
    __syncthreads();
    const float bc0 = bn0, bc1 = bn1;
    if (pf) {
#pragma unroll
      for (int i = 0; i < 2; ++i) {
        glds16(kg[i], Kn + (2 * w + i) * 512);
        glds16(vg[i], Vn + (2 * w + i) * 512);
        kg[i] += 32 * 2048;
        vg[i] += 32;
      }
      bn0 = brow[k0 + 32 + r16];
      bn1 = brow[k0 + 48 + r16];
    }
#pragma unroll
    for (int ct = 0; ct < 2; ++ct) {
      const int key = ct * 16 + r16;
      const int kb = key & 7;
      bf16x8 kf[4];
#pragma unroll
      for (int c = 0; c < 4; ++c)
        kf[c] = *(const bf16x8*)(Kc + key * 128 + ((4 * c + quad) ^ kb) * 8);
      const float bv = ct ? bc1 : bc0;
      const int pc = ct * 2 + (r16 >> 3);
#pragma unroll
      for (int t = 0; t < 2; ++t) {
        f32x4 s = {};
#pragma unroll
        for (int c = 0; c < 4; ++c)
          s = __builtin_amdgcn_mfma_f32_16x16x32_bf16(qf[t][c], kf[c], s, 0, 0, 0);
#pragma unroll
        for (int r = 0; r < 4; ++r) {
          const float p = __builtin_amdgcn_exp2f(s[r] + bv);
          const uint32_t pb = f_as_u(p) + 0x8000u;  // round-half-up to bf16
          const int row = t * 16 + quad * 4 + r;    // row&3 == r
          PsW[row * 40 + ((pc ^ r) << 3) + (r16 & 7)] = (uint16_t)(pb >> 16);
          li[t][r] += u_as_f(pb & 0xffff0000u);
        }
      }
    }
    bf16x8 pa[2];
#pragma unroll
    for (int t = 0; t < 2; ++t)
      pa[t] = *(const bf16x8*)(PsW + (t * 16 + r16) * 40 + ((quad ^ (r16 & 3)) << 3));
#pragma unroll
    for (int nt = 0; nt < 8; ++nt) {
      const int dim = nt * 16 + r16;
      bf16x8 vf = *(const bf16x8*)(Vc + dim * 32 + ((quad ^ (dim & 3)) << 3));
#pragma unroll
      for (int t = 0; t < 2; ++t)
        oacc[t][nt] = __builtin_amdgcn_mfma_f32_16x16x32_bf16(pa[t], vf, oacc[t][nt], 0, 0, 0);
    }
  };

  for (int kt2 = 0; kt2 < 32; ++kt2) {
    body(64 * kt2,      &Ks[0][0], &Vts[0][0], &Ks[1][0], &Vts[1][0], true);
    body(64 * kt2 + 32, &Ks[1][0], &Vts[1][0], &Ks[0][0], &Vts[0][0], kt2 < 31);
  }

#pragma unroll
  for (int off = 1; off < 16; off <<= 1)
#pragma unroll
    for (int t = 0; t < 2; ++t)
#pragma unroll
      for (int r = 0; r < 4; ++r) li[t][r] += __shfl_xor(li[t][r], off);

#pragma unroll
  for (int t = 0; t < 2; ++t) {
    uint16_t* ob = O + ((long)(b * 2048 + qbase + t * 16)) * 2048 + h * 128;
    float inv_l[4];
#pragma unroll
    for (int r = 0; r < 4; ++r) inv_l[r] = 1.0f / li[t][r];
#pragma unroll
    for (int nt = 0; nt < 8; ++nt)
#pragma unroll
      for (int r = 0; r < 4; ++r)
        ob[(long)(quad * 4 + r) * 2048 + nt * 16 + r16] = f2bf(oacc[t][nt][r] * inv_l[r]);
  }
}

extern "C" void kernel_launch(void* const* d_in, const int* in_sizes, int n_in,
                              void* d_out, int out_size, void* d_ws, size_t ws_size,
                              hipStream_t stream) {
  const float* x   = (const float*)d_in[0];
  const float* enc = (const float*)d_in[1];
  const int*   msk = (const int*)d_in[2];
  const float* Wq  = (const float*)d_in[3];
  const float* Wk  = (const float*)d_in[4];
  const float* Wv  = (const float*)d_in[5];
  const float* Wo  = (const float*)d_in[6];
  float* out = (float*)d_out;

  const long NELT = 8L * 1024 * 1024;  // 4096 x 2048 elems
  const long WELT = 4L * 1024 * 1024;  // 2048 x 2048 elems
  // d_ws (80 MiB + 16 KiB used): Qb[8M] Kb[8M] Vtb[8M] W4[16M] | bias
  uint16_t* Qb  = (uint16_t*)d_ws;
  uint16_t* Kb  = Qb + NELT;
  uint16_t* Vtb = Kb + NELT;
  uint16_t* W4  = Vtb + NELT;
  float* biasb  = (float*)(W4 + 4 * WELT);
  // d_out doubles as scratch for bf16 activations until the final GEMM overwrites it.
  uint16_t* xb   = (uint16_t*)d_out;        // 8M elems = 16 MB
  uint16_t* encb = xb + NELT;               // 8M elems = 16 MB (total 32 MB = out size)
  uint16_t* Ob   = W4;                      // Wq/Wk region dead after QKV GEMM

  const float cs_exp = 0.088388347648318447f * LOG2E;  // folded into Q

  convert_f32_bf16<<<(int)(NELT / 2048), 256, 0, stream>>>(x, xb);
  convert_f32_bf16<<<(int)(NELT / 2048), 256, 0, stream>>>(enc, encb);
  convert_w4<<<8192, 256, 0, stream>>>(Wq, Wk, Wv, Wo, W4);
  mask_bias<<<16, 256, 0, stream>>>(msk, biasb);

  // QKV mega-GEMM: N=6144, grid 48x32 = 1536 blocks (6 per CU)
  gemm_bt<EPI_QKV><<<dim3(48, 32), 256, 0, stream>>>(xb, encb, W4, Qb, Kb, Vtb,
                                                     4096, 6144, 2048, cs_exp);

  attn_kernel<<<dim3(16, 16, 2), 256, 0, stream>>>(Qb, Kb, Vtb, biasb, Ob);

  // Final projection: A = Ob (aliases dead Wq/Wk), W = Wo section of W4
  gemm_bt<EPI_F32><<<dim3(16, 32), 256, 0, stream>>>(Ob, nullptr, W4 + 3 * WELT,
                                                     out, nullptr, nullptr,
                                                     4096, 2048, 2048, 1.0f);
}